// Round 4
// baseline (75.197 us; speedup 1.0000x reference)
//
#include <hip/hip_runtime.h>
#include <cstdint>

#define PEDS   64
#define HIDDEN 128
#define POOL   64
#define GRIDG  4
#define NBHD   2.0f

typedef unsigned short u16;
typedef unsigned int   u32;
typedef __attribute__((ext_vector_type(8))) short bf16x8;
typedef __attribute__((ext_vector_type(4))) float f32x4;

__device__ __forceinline__ u16 f2bf(float f) {
    u32 u = __float_as_uint(f);
    u += 0x7fffu + ((u >> 16) & 1u);   // RNE
    return (u16)(u >> 16);
}
__device__ __forceinline__ u32 pack2bf(float a, float b) {
    return (u32)f2bf(a) | ((u32)f2bf(b) << 16);
}

// ============================================================
// prep: build fragment-native bf16 tables in d_ws.
//  hB[scene][mt][st4][lane] : h[row=scene*64+mt*16+(lane&15)][k0=st4*32+(lane>>4)*8 ..+8]
//  wB[g][cg][st4][lane]     : w^T[c=cg*16+(lane&15)][k0=st4*32+(lane>>4)*8 ..+8]
// Each thread produces one 16B fragment chunk.
// ============================================================
__global__ __launch_bounds__(256) void prep_kernel(
    const float* __restrict__ h, const float* __restrict__ w,
    u16* __restrict__ hB, u16* __restrict__ wB, int hb_threads)
{
    int t = blockIdx.x * 256 + threadIdx.x;
    if (t < hb_threads) {
        int lane = t & 63, st4 = (t >> 6) & 3, mt = (t >> 8) & 3, scene = t >> 10;
        int row = scene * 64 + mt * 16 + (lane & 15);
        int k0  = st4 * 32 + (lane >> 4) * 8;
        const float4* s = (const float4*)(h + (size_t)row * HIDDEN + k0);
        float4 f0 = s[0], f1 = s[1];
        *(uint4*)(hB + (size_t)t * 8) = make_uint4(
            pack2bf(f0.x, f0.y), pack2bf(f0.z, f0.w),
            pack2bf(f1.x, f1.y), pack2bf(f1.z, f1.w));
    } else {
        int u = t - hb_threads;
        if (u < 16 * 4 * 4 * 64) {
            int lane = u & 63, st4 = (u >> 6) & 3, cg = (u >> 8) & 3, g = u >> 10;
            int c  = cg * 16 + (lane & 15);
            int k0 = st4 * 32 + (lane >> 4) * 8;
            const float* s = w + ((size_t)g * HIDDEN + k0) * POOL + c;
            float v[8];
#pragma unroll
            for (int e = 0; e < 8; ++e) v[e] = s[(size_t)e * POOL];
            *(uint4*)(wB + (size_t)u * 8) = make_uint4(
                pack2bf(v[0], v[1]), pack2bf(v[2], v[3]),
                pack2bf(v[4], v[5]), pack2bf(v[6], v[7]));
        }
    }
}

// ============================================================
// main: 2 blocks per scene (channel halves), 256 threads (4 waves).
// Wave mt: GEMM1 j-rows mt*16..+16 (all slots, block's 32 c);
//          GEMM2 i-rows mt*16..+16.
// out = sum_g M_g @ (h @ W_g); gidx fully in-register per lane.
// LDS: wmask[4] + hwT bf16[32 c][256 k] (4 slots) = 16.1 KB.
// ============================================================
__global__ __launch_bounds__(256) void social_main(
    const u16* __restrict__ hB, const u16* __restrict__ wB,
    const float* __restrict__ pos, const float* __restrict__ bias,
    float* __restrict__ out)
{
    __shared__ u32 wmask[4];
    __shared__ u16 hwT[32 * 256];          // [cr][k], 16B chunks XOR-swizzled by cr&15

    const int tid  = threadIdx.x;
    const int mt   = tid >> 6;
    const int lane = tid & 63;
    const int l15  = lane & 15;
    const int q    = lane >> 4;
    const int scene = blockIdx.x >> 1;
    const int ch    = blockIdx.x & 1;

    // ---- A-fragments: one coalesced 16B load each (issued first) ----
    bf16x8 af[4];
    const u16* hfb = hB + (((size_t)scene * 4 + mt) * 4) * 512;
#pragma unroll
    for (int st4 = 0; st4 < 4; ++st4)
        af[st4] = *(const bf16x8*)(hfb + st4 * 512 + lane * 8);

    const float bv0 = bias[ch * 32 + l15];
    const float bv1 = bias[ch * 32 + 16 + l15];

    // ---- positions & in-register gidx for exactly the pairs this lane needs ----
    float2 pp = ((const float2*)pos)[(size_t)scene * PEDS + lane];
    const int i = mt * 16 + l15;
    const float pxi = __shfl(pp.x, i), pyi = __shfl(pp.y, i);
    const float scale = (float)GRIDG / (2.0f * NBHD);
    u32 gpk[4] = {0u, 0u, 0u, 0u};
    u32 um = 0u;
#pragma unroll
    for (int jh = 0; jh < 2; ++jh) {
#pragma unroll
        for (int u8 = 0; u8 < 8; ++u8) {
            int j = jh * 32 + q * 8 + u8;
            float rx = __shfl(pp.x, j) - pxi;
            float ry = __shfl(pp.y, j) - pyi;
            u32 gb = 0xffu;
            if ((i != j) && (fabsf(rx) <= NBHD) && (fabsf(ry) <= NBHD)) {
                int gx = (int)floorf((rx + NBHD) * scale); gx = min(max(gx, 0), GRIDG - 1);
                int gy = (int)floorf((ry + NBHD) * scale); gy = min(max(gy, 0), GRIDG - 1);
                gb = (u32)(gy * GRIDG + gx);
                um |= 1u << gb;
            }
            gpk[jh * 2 + (u8 >> 2)] |= gb << ((u8 & 3) * 8);
        }
    }
#pragma unroll
    for (int off = 32; off; off >>= 1) um |= __shfl_xor(um, off);
    if (lane == 0) wmask[mt] = um;
    __syncthreads();                                   // B1: wmask

    u32 mask = wmask[0] | wmask[1] | wmask[2] | wmask[3];
    mask = __builtin_amdgcn_readfirstlane(mask);

    f32x4 oacc0 = (f32x4){0.f, 0.f, 0.f, 0.f};
    f32x4 oacc1 = (f32x4){0.f, 0.f, 0.f, 0.f};
    u32 rem = mask;

    while (true) {
        int gs[4];
#pragma unroll
        for (int t = 0; t < 4; ++t) {
            gs[t] = rem ? (__ffs(rem) - 1) : -1;
            if (rem) rem &= rem - 1u;
        }

        // ---- GEMM1: hw_g[j, c] for 4 slots; inactive slots compute cell 0 (masked later) ----
#pragma unroll
        for (int t = 0; t < 4; ++t) {
            int ge = gs[t] < 0 ? 0 : gs[t];
            const u16* wf0 = wB + (((size_t)ge * 4 + ch * 2 + 0) * 4) * 512;
            const u16* wf1 = wB + (((size_t)ge * 4 + ch * 2 + 1) * 4) * 512;
            f32x4 a10 = (f32x4){0.f, 0.f, 0.f, 0.f};
            f32x4 a11 = (f32x4){0.f, 0.f, 0.f, 0.f};
#pragma unroll
            for (int st4 = 0; st4 < 4; ++st4) {
                bf16x8 b0 = *(const bf16x8*)(wf0 + st4 * 512 + lane * 8);
                bf16x8 b1 = *(const bf16x8*)(wf1 + st4 * 512 + lane * 8);
                a10 = __builtin_amdgcn_mfma_f32_16x16x32_bf16(af[st4], b0, a10, 0, 0, 0);
                a11 = __builtin_amdgcn_mfma_f32_16x16x32_bf16(af[st4], b1, a11, 0, 0, 0);
            }
            // store: k = t*64 + mt*16 + q*4 + r at row cr, 16B-chunk XOR cr&15
            int ci = t * 8 + mt * 2 + (q >> 1);
#pragma unroll
            for (int ni = 0; ni < 2; ++ni) {
                const f32x4& a = ni ? a11 : a10;
                int cr  = ni * 16 + l15;
                int ci2 = (ci & 0x10) | ((ci & 15) ^ l15);
                *(uint2*)&hwT[cr * 256 + ci2 * 8 + (q & 1) * 4] =
                    make_uint2(pack2bf(a[0], a[1]), pack2bf(a[2], a[3]));
            }
        }
        __syncthreads();                               // B2: hwT complete

        // ---- GEMM2: oacc += M @ hwT, K = 256 over (slot, j) ----
#pragma unroll
        for (int step = 0; step < 8; ++step) {
            int slot = step >> 1, jh = step & 1;
            int gt = gs[slot];
            u32 wa = gpk[jh * 2], wb = gpk[jh * 2 + 1];
            union { u16 hx[8]; bf16x8 v; } mu;
#pragma unroll
            for (int b = 0; b < 4; ++b)
                mu.hx[b]     = (((wa >> (b * 8)) & 0xffu) == (u32)gt) ? (u16)0x3F80 : (u16)0;
#pragma unroll
            for (int b = 0; b < 4; ++b)
                mu.hx[4 + b] = (((wb >> (b * 8)) & 0xffu) == (u32)gt) ? (u16)0x3F80 : (u16)0;
            int ci = step * 4 + q;
#pragma unroll
            for (int ni = 0; ni < 2; ++ni) {
                int cr  = ni * 16 + l15;
                int ci2 = (ci & 0x10) | ((ci & 15) ^ l15);
                bf16x8 bb = *(const bf16x8*)&hwT[cr * 256 + ci2 * 8];
                if (ni == 0)
                    oacc0 = __builtin_amdgcn_mfma_f32_16x16x32_bf16(mu.v, bb, oacc0, 0, 0, 0);
                else
                    oacc1 = __builtin_amdgcn_mfma_f32_16x16x32_bf16(mu.v, bb, oacc1, 0, 0, 0);
            }
        }
        if (!rem) break;
        __syncthreads();                               // B3: hwT reusable
    }

    // ---- epilogue: i = mt*16+q*4+r, c = ch*32 + ni*16 + l15 ----
    size_t ob = ((size_t)scene * PEDS + mt * 16 + q * 4) * POOL + ch * 32 + l15;
#pragma unroll
    for (int r = 0; r < 4; ++r) {
        out[ob + (size_t)r * POOL]      = oacc0[r] + bv0;
        out[ob + (size_t)r * POOL + 16] = oacc1[r] + bv1;
    }
}

extern "C" void kernel_launch(void* const* d_in, const int* in_sizes, int n_in,
                              void* d_out, int out_size, void* d_ws, size_t ws_size,
                              hipStream_t stream) {
    const float* h    = (const float*)d_in[0];
    const float* pos  = (const float*)d_in[1];
    const float* w    = (const float*)d_in[2];
    const float* bias = (const float*)d_in[3];
    float* out = (float*)d_out;

    const int total = in_sizes[0] / HIDDEN;   // 16384
    const int B     = total / PEDS;           // 256

    u16* hB = (u16*)d_ws;                               // total*128 bf16 = 4 MB
    u16* wB = hB + (size_t)total * HIDDEN;              // 16*4*4*64*8 u16 = 256 KB

    const int hb_threads = total * 16;                  // one 16B chunk per thread
    const int wb_threads = 16 * 4 * 4 * 64;
    const int prep_blocks = (hb_threads + wb_threads + 255) / 256;

    hipLaunchKernelGGL(prep_kernel, dim3(prep_blocks), dim3(256), 0, stream,
                       h, w, hB, wB, hb_threads);
    hipLaunchKernelGGL(social_main, dim3(B * 2), dim3(256), 0, stream,
                       hB, wB, pos, bias, out);
}